// Round 15
// baseline (1106.297 us; speedup 1.0000x reference)
//
#include <hip/hip_runtime.h>
#include <hip/hip_bf16.h>

#define DEV __device__ __forceinline__

typedef __bf16 bf16x8 __attribute__((ext_vector_type(8)));
typedef float  f32x4  __attribute__((ext_vector_type(4)));
typedef unsigned short u16;

DEV u16   f2b(float f) { __bf16 h = (__bf16)f; return __builtin_bit_cast(u16, h); }
DEV float b2f(u16 x)   { return __builtin_bit_cast(float, ((unsigned)x) << 16); }

DEV void gl_lds16(const u16* g, u16* l) {
  __builtin_amdgcn_global_load_lds((const __attribute__((address_space(1))) void*)g,
                                   (__attribute__((address_space(3))) void*)l, 16, 0, 0);
}

// row map: S>0 -> ((m>>3)*S + j)*8 + (m&7); S==0 -> m; S<0 -> m&7 (replicate)
DEV long arow(int m, int S, int j) {
  if (S > 0)  return ((long)((m >> 3) * S + j)) * 8 + (m & 7);
  if (S == 0) return m;
  return m & 7;
}

// ---------------------------------------------------------------------------
// Unified segment-GEMM (runtime mode, z-fusable): D[m,e]=sum_seg A_seg*B_seg^T
// 64x64 tile, BK=128 double-buffered LDS (proven core).
// mode 0: squaring; mode 2: ph1/ph2; mode 3: ph3 (hall/out0/silu epilogue).
// XCD swizzle ONLY when the z-slice fills the grid (ylim==gridDim.y) —
// trimmed slices use identity fid (round-robin across XCDs, stays balanced).
// ---------------------------------------------------------------------------
struct ZCfg {
  const u16 *A0, *A1, *A2, *A3, *A4;
  const u16 *B0, *B1, *B2, *B3, *B4;
  int S0, J0, S1, J1, S2, J2, S3, J3, S4, J4;
  int nseg, mvalid, q, mode, ylim;
  const float* addc;
  const float* addf;
  const u16*   addb; int addS, addJ;
  float* outf;
  u16 *outb, *outbT, *outlo;
  u16* outm; int oS, oJ;
  u16 *glamH, *glamL;
  float *hall, *out0;
};
struct GArgs { ZCfg z0, z1, z2, z3; };

__global__ __launch_bounds__(256) void gU(GArgs ga)
{
  ZCfg c;
  switch (blockIdx.z) { case 0: c = ga.z0; break; case 1: c = ga.z1; break;
                        case 2: c = ga.z2; break; default: c = ga.z3; break; }

  int gx = gridDim.x;
  int fid = blockIdx.y * gx + blockIdx.x;
  int nwg = gx * gridDim.y;
  int idx = (c.ylim == (int)gridDim.y) ? ((fid & 7) * (nwg >> 3) + (fid >> 3))
                                       : fid;
  int mt = idx / gx, et = idx % gx;
  if (mt >= c.ylim) return;
  int m0 = mt << 6, e0 = et << 6;

  const int K = c.nseg << 10;
  int tid = threadIdx.x, lane = tid & 63, w = tid >> 6;
  int wrow = (w >> 1) << 5, wcol = (w & 1) << 5;

  __shared__ u16 As[2][8192], Bs[2][8192];
  f32x4 acc[2][2] = {};

  int rA[4], cA[4];
#pragma unroll
  for (int j = 0; j < 4; ++j) {
    int p = (j * 4 + w) * 1024 + lane * 16;
    int r = p >> 8, o = (p & 255) ^ ((r & 7) << 4);
    rA[j] = r; cA[j] = o >> 1;
  }
  auto seg = [&](int i, const u16*& A, int& S, int& J, const u16*& B) {
    switch (i) {
      case 0: A = c.A0; S = c.S0; J = c.J0; B = c.B0; break;
      case 1: A = c.A1; S = c.S1; J = c.J1; B = c.B1; break;
      case 2: A = c.A2; S = c.S2; J = c.J2; B = c.B2; break;
      case 3: A = c.A3; S = c.S3; J = c.J3; B = c.B3; break;
      default: A = c.A4; S = c.S4; J = c.J4; B = c.B4; break;
    }
  };
  auto stage = [&](int buf, int kt) {
    int si = kt >> 10, kl = kt & 1023;
    const u16 *A, *B; int S, J;
    seg(si, A, S, J, B);
#pragma unroll
    for (int j = 0; j < 4; ++j) {
      int grow = m0 + rA[j];
      gl_lds16(A + arow(grow, S, J) * 1024 + kl + cA[j], &As[buf][(j * 4 + w) * 512]);
    }
#pragma unroll
    for (int j = 0; j < 4; ++j)
      gl_lds16(B + (size_t)(e0 + rA[j]) * 1024 + kl + cA[j], &Bs[buf][(j * 4 + w) * 512]);
  };

  stage(0, 0);
  asm volatile("s_waitcnt vmcnt(0)" ::: "memory");
  __syncthreads();

  int buf = 0;
  for (int kt = 0; kt < K; kt += 128, buf ^= 1) {
    if (kt + 128 < K) stage(buf ^ 1, kt + 128);
#pragma unroll
    for (int ks = 0; ks < 4; ++ks) {
      int oa = ks * 64 + ((lane >> 4) << 4);
      bf16x8 af[2], bf[2];
#pragma unroll
      for (int s = 0; s < 2; ++s) {
        int ra = wrow + s * 16 + (lane & 15);
        int rb = wcol + s * 16 + (lane & 15);
        af[s] = *(const bf16x8*)((const char*)&As[buf][0] + ra * 256 + (oa ^ ((ra & 7) << 4)));
        bf[s] = *(const bf16x8*)((const char*)&Bs[buf][0] + rb * 256 + (oa ^ ((rb & 7) << 4)));
      }
#pragma unroll
      for (int ms = 0; ms < 2; ++ms)
#pragma unroll
        for (int ns = 0; ns < 2; ++ns)
          acc[ms][ns] = __builtin_amdgcn_mfma_f32_16x16x32_bf16(af[ms], bf[ns], acc[ms][ns], 0, 0, 0);
    }
    asm volatile("s_waitcnt vmcnt(0)" ::: "memory");
    __syncthreads();
  }

  int l4 = ((lane >> 4) << 2), lc = lane & 15;
#pragma unroll
  for (int ms = 0; ms < 2; ++ms)
#pragma unroll
    for (int ns = 0; ns < 2; ++ns)
#pragma unroll
      for (int j = 0; j < 4; ++j) {
        int row = m0 + wrow + ms * 16 + l4 + j;   // C/D: row=(lane>>4)*4+reg
        int col = e0 + wcol + ns * 16 + lc;       // C/D: col=lane&15
        float v = acc[ms][ns][j];
        if (c.mode == 0) {
          u16 h = f2b(v);
          if (c.outb)  c.outb[(size_t)row * 1024 + col] = h;
          if (c.outbT) c.outbT[(size_t)col * 1024 + row] = h;
        } else if (c.mode == 2) {
          if (c.addc) v += c.addc[col];
          if (c.addb)      v += b2f(c.addb[arow(row, c.addS, c.addJ) * 1024 + col]);
          else if (c.addf) v += c.addf[arow(row, c.addS, c.addJ) * 1024 + col];
          if (row < c.mvalid) {
            if (c.outf) c.outf[(size_t)row * 1024 + col] = v;
            u16 hi = f2b(v);
            if (c.outb)  c.outb[(size_t)row * 1024 + col] = hi;
            if (c.outlo) c.outlo[(size_t)row * 1024 + col] = f2b(v - b2f(hi));
            if (c.outm)  c.outm[arow(row, c.oS, c.oJ) * 1024 + col] = hi;
            if (c.glamH && ((row >> 3) & 15) == 0) {     // fused Lambda_1 gather
              int r2 = ((row >> 3) >> 4) * 8 + (row & 7);
              c.glamH[(size_t)r2 * 1024 + col] = hi;
              c.glamL[(size_t)r2 * 1024 + col] = f2b(v - b2f(hi));
            }
          }
        } else {
          v += b2f(c.addb[arow(row, c.addS, c.addJ) * 1024 + col]);
          int t = (row >> 3) * 4 + c.q, b = row & 7;
          c.hall[(size_t)t * 8192 + b * 1024 + col] = v;
          float sg = 1.f / (1.f + __expf(-v));
          c.out0[(size_t)(t - 1) * 8192 + b * 1024 + col] = v * v * sg;
          if (c.outb) c.outb[(size_t)row * 1024 + col] = f2b(v);
        }
      }
}

// ---- power iteration (normalization-free) + misc helpers --------------------
// k_init zeroes the 6 matvec accumulators each launch (graph-replay-safe).
__global__ void k_init(const float* __restrict__ h0, float* __restrict__ accs,
                       float* __restrict__ hall0, u16* __restrict__ bndSb,
                       u16* __restrict__ bndSlo, u16* __restrict__ bndb)
{
  int i = blockIdx.x * 256 + threadIdx.x;
  if (i < 6144) accs[i] = 0.f;
  if (i < 8192) {
    float h = h0[i];
    hall0[i] = h;
    u16 hi = f2b(h);
    bndSb[i] = hi;
    bndSlo[i] = f2b(h - b2f(hi));
    bndb[i] = hi;
  }
}

// acc[d] += sum_{e in block} W[e,d]*x[e]   (y = W^T x)
__global__ void k_v(const float* __restrict__ W, const float* __restrict__ x,
                    float* __restrict__ acc)
{
  int d = blockIdx.x * 256 + threadIdx.x;
  int e0 = blockIdx.y * 64;
  float a = 0.f;
  for (int e = e0; e < e0 + 64; ++e) a += W[(size_t)e * 1024 + d] * x[e];
  atomicAdd(&acc[d], a);
}

// acc[e] += W[e,:] . x   (y = W x)
__global__ void k_u(const float* __restrict__ W, const float* __restrict__ x,
                    float* __restrict__ acc)
{
  int lg = threadIdx.x & 15, ei = threadIdx.x >> 4;
  int e = blockIdx.y * 16 + ei;
  int d0 = blockIdx.x * 512;
  float a = 0.f;
  for (int i = 0; i < 32; ++i) { int d = d0 + lg + 16 * i; a += W[(size_t)e * 1024 + d] * x[d]; }
#pragma unroll
  for (int m = 1; m < 16; m <<= 1) a += __shfl_xor(a, m);
  if (lg == 0) atomicAdd(&acc[e], a);
}

// sigma = ||Ws|| / (||s||+eps); sigma_eff = sigma^2/(sigma+eps);
// scale = 0.95/(sigma_eff+eps)
__global__ void k_sigma2(const float* __restrict__ s, const float* __restrict__ wsv,
                         float* __restrict__ scale)
{
  __shared__ float red[32];
  int t = threadIdx.x;
  float a = s[t], b = wsv[t];
  float sa = a * a, sb = b * b;
#pragma unroll
  for (int m = 1; m < 64; m <<= 1) { sa += __shfl_xor(sa, m); sb += __shfl_xor(sb, m); }
  if ((t & 63) == 0) { red[(t >> 6) * 2] = sa; red[(t >> 6) * 2 + 1] = sb; }
  __syncthreads();
  if (t == 0) {
    float ns = 0.f, nw = 0.f;
    for (int i = 0; i < 16; ++i) { ns += red[i * 2]; nw += red[i * 2 + 1]; }
    ns = sqrtf(ns); nw = sqrtf(nw);
    float sigma = nw / (ns + 1e-8f);
    float se = sigma * sigma / (sigma + 1e-8f);
    scale[0] = 0.95f / (se + 1e-8f);
  }
}

__global__ void k_prep(const float* __restrict__ Wh, const float* __restrict__ Wx,
                       const float* __restrict__ scale, u16* __restrict__ wh_b,
                       u16* __restrict__ whT, u16* __restrict__ wxb)
{
  int i = blockIdx.x * 256 + threadIdx.x;
  float s = scale[0];
  int e = i >> 10, d = i & 1023;
  u16 hw = f2b(Wh[i] * s);
  wh_b[i] = hw;
  whT[(size_t)d * 1024 + e] = hw;
  wxb[i] = f2b(Wx[i]);
}

__global__ void k_cvt(const float* __restrict__ in, u16* __restrict__ out, int n)
{
  int i = (blockIdx.x * 256 + threadIdx.x) * 4;
  if (i >= n) return;
  float4 v = *(const float4*)(in + i);
  ushort4 o;
  o.x = f2b(v.x); o.y = f2b(v.y); o.z = f2b(v.z); o.w = f2b(v.w);
  *(ushort4*)(out + i) = o;
}

static void setseg(ZCfg& z, int i, const u16* A, int S, int J, const u16* B) {
  switch (i) {
    case 0: z.A0 = A; z.S0 = S; z.J0 = J; z.B0 = B; break;
    case 1: z.A1 = A; z.S1 = S; z.J1 = J; z.B1 = B; break;
    case 2: z.A2 = A; z.S2 = S; z.J2 = J; z.B2 = B; break;
    case 3: z.A3 = A; z.S3 = S; z.J3 = J; z.B3 = B; break;
    default: z.A4 = A; z.S4 = S; z.J4 = J; z.B4 = B; break;
  }
}
static void setsq(ZCfg& z, const u16* A, const u16* B, u16* o, u16* oT) {
  z.A0 = A; z.S0 = 0; z.J0 = 0; z.B0 = B; z.nseg = 1;
  z.outb = o; z.outbT = oT; z.mode = 0; z.ylim = 16;
}

extern "C" void kernel_launch(void* const* d_in, const int* in_sizes, int n_in,
                              void* d_out, int out_size, void* d_ws, size_t ws_size,
                              hipStream_t stream)
{
  (void)in_sizes; (void)n_in; (void)out_size; (void)ws_size;
  const float* x  = (const float*)d_in[0];
  const float* h0 = (const float*)d_in[1];
  const float* Wx = (const float*)d_in[2];
  const float* Wh = (const float*)d_in[3];
  const float* bv = (const float*)d_in[4];
  const float* uv = (const float*)d_in[5];

  float* out0 = (float*)d_out;
  float* hall = out0 + 16777216;

  const size_t M1 = 1048576;
  // ---- ws: everything phase 3 reads + small state ----
  char* ws = (char*)d_ws;
  u16*   pre_b = (u16*)(ws);                  // 32 MiB [16384,1024] bf16
  u16*   wh_b  = (u16*)(ws + 32 * M1);        // 2 MiB
  u16*   bnd_b = (u16*)(ws + 34 * M1);        // 8 MiB [4096,1024]
  u16*   lb0   = (u16*)(ws + 42 * M1);        // 8 MiB phase-3 chain
  u16*   bndSb = (u16*)(ws + 50 * M1);        // 512 KiB [256,1024]
  u16*   bndSlo= (u16*)(ws + 50 * M1 + 524288);
  float* accs  = (float*)(ws + 51 * M1);      // 6 x 1024 matvec accumulators
  float* scale = accs + 6144;
  u16*   W2    = (u16*)(ws + 52 * M1);        // 2 MiB — read by phase 3!

  // ---- hall scratch (HBS = hall + 32 KiB; dead before phase 3) ----
  char* HBS = (char*)hall + 32768;
  u16*   xb   = (u16*)(HBS);                   // 32 MiB (dead after pre-GEMM)
  float* lC   = (float*)(HBS);                 // 16 MiB (over xb)
  u16*   lCb  = (u16*)(HBS + 16 * M1);         // 8 MiB
  float* lamF = (float*)(HBS + 24 * M1);       // 1 MiB
  u16* lamH0  = (u16*)(HBS + 25 * M1);
  u16* lamH1  = (u16*)(HBS + 25 * M1 + 524288);
  u16* lamL0  = (u16*)(HBS + 26 * M1);
  u16* lamL1  = (u16*)(HBS + 26 * M1 + 524288);
  u16* pcH0   = (u16*)(HBS + 27 * M1);
  u16* pcH1   = (u16*)(HBS + 27 * M1 + 524288);
  u16* pcL0   = (u16*)(HBS + 28 * M1);
  u16* pcL1   = (u16*)(HBS + 28 * M1 + 524288);
  auto slot = [&](int k) { return (u16*)(HBS + 32 * M1 + (size_t)k * 2 * M1); };
  u16* whT  = slot(0);   // -> W192 later
  u16* wxb  = slot(1);   // -> W256 later
  u16* W2T  = slot(3);
  u16* W3   = slot(4);
  u16* W4   = slot(5);
  u16* W4T  = slot(6);
  u16* W8   = slot(7);
  u16* W8T  = slot(8);   // -> W128 later
  u16* W12  = slot(9);
  u16* W16  = slot(10);
  u16* W16T = slot(11);  // -> W128T later
  u16* W32  = slot(12);
  u16* W32T = slot(13);
  u16* W64  = slot(14);
  u16* W64T = slot(15);
  u16* W128 = W8T, *W128T = W16T, *W192 = whT, *W256 = wxb;

  k_init<<<32, 256, 0, stream>>>(h0, accs, hall, bndSb, bndSlo, bnd_b);

  // power iteration, normalization-free: s = Wt W Wt W Wt u0; sigma=||Ws||/||s||
  float* a0 = accs, *a1 = accs + 1024, *a2 = accs + 2048;
  float* a3 = accs + 3072, *a4 = accs + 4096, *a5 = accs + 5120;
  k_v<<<dim3(4, 16), 256, 0, stream>>>(Wh, uv, a0);
  k_u<<<dim3(2, 64), 256, 0, stream>>>(Wh, a0, a1);
  k_v<<<dim3(4, 16), 256, 0, stream>>>(Wh, a1, a2);
  k_u<<<dim3(2, 64), 256, 0, stream>>>(Wh, a2, a3);
  k_v<<<dim3(4, 16), 256, 0, stream>>>(Wh, a3, a4);
  k_u<<<dim3(2, 64), 256, 0, stream>>>(Wh, a4, a5);
  k_sigma2<<<1, 1024, 0, stream>>>(a4, a5, scale);

  k_prep<<<4096, 256, 0, stream>>>(Wh, Wx, scale, wh_b, whT, wxb);
  k_cvt<<<16384, 256, 0, stream>>>(x, xb, 16777216);

  // a) pre = x @ Wx^T + b (bf16)  ∥  S1: W2 (-> ws)
  { GArgs a{}; ZCfg& z = a.z0;
    setseg(z, 0, xb, 0, 0, wxb);
    z.nseg = 1; z.mode = 2; z.ylim = 256; z.mvalid = 16384;
    z.addc = bv; z.outb = pre_b;
    setsq(a.z1, wh_b, whT, W2, W2T);
    gU<<<dim3(16, 256, 2), 256, 0, stream>>>(a); }

  // b) S2: W3, W4
  { GArgs a{}; setsq(a.z0, W2, whT, W3, nullptr); setsq(a.z1, W2, W2T, W4, W4T);
    gU<<<dim3(16, 16, 2), 256, 0, stream>>>(a); }

  // c) phase 1 (lC = W3 p0 + W2 p1 + W p2 + p3, gather fused)  ∥  S3: W8
  { GArgs a{}; ZCfg& z = a.z0;
    setseg(z, 0, pre_b, 4, 0, W3);
    setseg(z, 1, pre_b, 4, 1, W2);
    setseg(z, 2, pre_b, 4, 2, wh_b);
    z.nseg = 3; z.mode = 2; z.ylim = 64; z.mvalid = 4096;
    z.addb = pre_b; z.addS = 4; z.addJ = 3;
    z.outf = lC; z.outb = lCb;
    z.glamH = lamH0; z.glamL = lamL0;
    setsq(a.z1, W4, W4T, W8, W8T);
    gU<<<dim3(16, 64, 2), 256, 0, stream>>>(a); }

  // d) S4: W12, W16
  { GArgs a{}; setsq(a.z0, W8, W4T, W12, nullptr); setsq(a.z1, W8, W8T, W16, W16T);
    gU<<<dim3(16, 16, 2), 256, 0, stream>>>(a); }

  // e..h) phase 2a Lambda chain  ∥  S5..S8
  {
    const u16 *chH = lamH0, *chL = lamL0;
    int j0s[3] = {1, 5, 9};
    u16* nxH[3] = { lamH1, lamH0, lamH1 };
    u16* nxL[3] = { lamL1, lamL0, lamL1 };
    const u16* sqA[3] = { W16, W32, W64 };
    const u16* sqB[3] = { W16T, W32T, W64T };
    u16* sqO[3] = { W32, W64, W128 };
    u16* sqT[3] = { W32T, W64T, W128T };
    for (int i = 0; i < 3; ++i) {
      GArgs a{}; ZCfg& z = a.z0;
      setseg(z, 0, chH, 0, 0, W16); setseg(z, 1, chL, 0, 0, W16);
      setseg(z, 2, lCb, 16, j0s[i],     W12);
      setseg(z, 3, lCb, 16, j0s[i] + 1, W8);
      setseg(z, 4, lCb, 16, j0s[i] + 2, W4);
      z.nseg = 5; z.mode = 2; z.ylim = 4; z.mvalid = 256;
      z.addf = lC; z.addS = 16; z.addJ = j0s[i] + 3;
      z.outb = nxH[i]; z.outlo = nxL[i];
      setsq(a.z1, sqA[i], sqB[i], sqO[i], sqT[i]);
      gU<<<dim3(16, 16, 2), 256, 0, stream>>>(a);
      chH = nxH[i]; chL = nxL[i];
    }
    GArgs a{}; ZCfg& z = a.z0;   // Lambda16 final
    setseg(z, 0, chH, 0, 0, W12); setseg(z, 1, chL, 0, 0, W12);
    setseg(z, 2, lCb, 16, 13, W8); setseg(z, 3, lCb, 16, 14, W4);
    z.nseg = 4; z.mode = 2; z.ylim = 4; z.mvalid = 256;
    z.addf = lC; z.addS = 16; z.addJ = 15;
    z.outf = lamF; z.outb = lamH0; z.outlo = lamL0;
    setsq(a.z1, W128, W64T, W192, nullptr);
    setsq(a.z2, W128, W128T, W256, nullptr);
    gU<<<dim3(16, 16, 3), 256, 0, stream>>>(a);
  }

  // i..p) phase 2b: superchunk chain, 8 z-quad launches (M=8)
  {
    const u16* w64s[4] = { W64, W128, W192, W256 };
    for (int sb2 = 0; sb2 < 32; sb2 += 4) {
      int zmax = (sb2 == 28) ? 3 : 4;
      GArgs a{};
      ZCfg* zs[4] = { &a.z0, &a.z1, &a.z2, &a.z3 };
      for (int zz = 1; zz <= zmax; ++zz) {
        ZCfg& z = *zs[zz - 1];
        setseg(z, 0, bndSb + (size_t)sb2 * 8192, -1, 0, w64s[zz - 1]);
        int ns = 1;
        for (int i = 0; i < zz - 1; ++i)
          setseg(z, ns++, lamH0 + (size_t)(sb2 + i) * 8192, -1, 0, w64s[zz - 2 - i]);
        z.nseg = ns; z.mode = 2; z.ylim = 1; z.mvalid = 8;
        z.addf = lamF + (size_t)(sb2 + zz - 1) * 8192; z.addS = -1;
        z.outb = bndSb + (size_t)(sb2 + zz) * 8192;
        z.outlo = bndSlo + (size_t)(sb2 + zz) * 8192;
        z.outm = bnd_b + (size_t)16 * (sb2 + zz) * 8192; z.oS = 0;
      }
      gU<<<dim3(16, 1, zmax), 256, 0, stream>>>(a);
    }
  }

  // q..t) phase 2c: intra-super chunk boundaries, 4 z-quad launches
  {
    const u16* w4s[4] = { W4, W8, W12, W16 };
    const u16* cinH[4] = { bndSb, pcH0, pcH1, pcH0 };
    const u16* cinL[4] = { bndSlo, pcL0, pcL1, pcL0 };
    u16* coutH[4] = { pcH0, pcH1, pcH0, nullptr };
    u16* coutL[4] = { pcL0, pcL1, pcL0, nullptr };
    for (int t4 = 0; t4 < 4; ++t4) {
      int jb = 4 * t4;
      int zmax = (t4 == 3) ? 3 : 4;
      GArgs a{};
      ZCfg* zs[4] = { &a.z0, &a.z1, &a.z2, &a.z3 };
      for (int zz = 1; zz <= zmax; ++zz) {
        ZCfg& z = *zs[zz - 1];
        setseg(z, 0, cinH[t4], 0, 0, w4s[zz - 1]);
        setseg(z, 1, cinL[t4], 0, 0, w4s[zz - 1]);
        int ns = 2;
        for (int i = 0; i < zz - 1; ++i)
          setseg(z, ns++, lCb, 16, jb + i, w4s[zz - 2 - i]);
        z.nseg = ns; z.mode = 2; z.ylim = 4; z.mvalid = 256;
        z.addf = lC; z.addS = 16; z.addJ = jb + zz - 1;
        z.outm = bnd_b; z.oS = 16; z.oJ = jb + zz;
        if (zz == 4) { z.outb = coutH[t4]; z.outlo = coutL[t4]; }
      }
      gU<<<dim3(16, 4, zmax), 256, 0, stream>>>(a);
    }
  }

  // u,v) phase 3: 2 launches, z=2 each: {h1, h2} then {h3, h4}
  {
    const u16* chains[2] = { bnd_b, lb0 };
    u16* chouts[2] = { lb0, nullptr };
    for (int half = 0; half < 2; ++half) {
      int qa = 2 * half + 1;      // 1 or 3
      GArgs a{};
      { ZCfg& z = a.z0;           // h_odd = W * chain + p_even
        setseg(z, 0, chains[half], 0, 0, wh_b);
        z.nseg = 1; z.mode = 3; z.ylim = 64; z.q = qa;
        z.addb = pre_b; z.addS = 4; z.addJ = qa - 1;
        z.hall = hall; z.out0 = out0; }
      { ZCfg& z = a.z1;           // h_even = W2 * chain + W * p_even + p_odd
        setseg(z, 0, chains[half], 0, 0, W2);
        setseg(z, 1, pre_b, 4, qa - 1, wh_b);
        z.nseg = 2; z.mode = 3; z.ylim = 64; z.q = qa + 1;
        z.addb = pre_b; z.addS = 4; z.addJ = qa;
        z.hall = hall; z.out0 = out0;
        z.outb = chouts[half]; }
      gU<<<dim3(16, 64, 2), 256, 0, stream>>>(a);
    }
  }
}